// Round 8
// baseline (12662.697 us; speedup 1.0000x reference)
//
#include <hip/hip_runtime.h>
#include <stdint.h>
#include <stddef.h>

#define NB 1024
#define TB 1024
#define D_IN 6
#define UNITS 64
#define WIDTH 128
#define DOUT 6
#define EPSF 1e-8f
#define SPB 16          // samples per tile (one 16-row MFMA tile)
#define TPB 2           // tiles per block
#define LDK0 108        // c0 row stride (halfs): conflict-free (54 dw == 22 mod 32)
#define LDK 140         // cP/cQ/cG row stride (halfs): conflict-free (70 dw == 6 mod 32)

typedef _Float16 v8h __attribute__((ext_vector_type(8)));
typedef float v4f __attribute__((ext_vector_type(4)));

#define MFMAH(A,Bf,C) __builtin_amdgcn_mfma_f32_16x16x32_f16((A),(Bf),(C),0,0,0)

// LDS-only barrier: orders LDS across the block, does NOT drain vmcnt.
#define BARRIER_LDS() asm volatile("s_waitcnt lgkmcnt(0)\n\ts_barrier" ::: "memory")

__device__ __forceinline__ float rcp_fast(float x){ return __builtin_amdgcn_rcpf(x); }

// Pade(7,6) tanh on VALU pipe (1 fast-rcp, no exp). Clamp +-5.
__device__ __forceinline__ float tanh_r(float x){
  float t = fminf(fmaxf(x, -5.0f), 5.0f);
  float s = t * t;
  float num = t * fmaf(s, fmaf(s, (s + 378.0f), 17325.0f), 135135.0f);
  float den = fmaf(s, fmaf(s, fmaf(s, 28.0f, 3150.0f), 62370.0f), 135135.0f);
  return num * rcp_fast(den);
}

__device__ __forceinline__ void make_frag1(const float* vals, v8h& hv){
  #pragma unroll
  for (int j = 0; j < 8; j++) hv[j] = (_Float16)vals[j];
}
__device__ __forceinline__ void make_frag2(const float* vals, v8h& hv, v8h& lv){
  #pragma unroll
  for (int j = 0; j < 8; j++){
    _Float16 h = (_Float16)vals[j];
    hv[j] = h;
    lv[j] = (_Float16)(vals[j] - (float)h);
  }
}

__global__ __launch_bounds__(1024, 4) void lmsc_kernel(
    const float* __restrict__ x, const float* __restrict__ initF,
    const float* __restrict__ w10, const float* __restrict__ b10,
    const float* __restrict__ w20, const float* __restrict__ b20,
    const float* __restrict__ w11, const float* __restrict__ b11,
    const float* __restrict__ w21, const float* __restrict__ b21,
    const float* __restrict__ w12, const float* __restrict__ b12,
    const float* __restrict__ w22, const float* __restrict__ b22,
    const float* __restrict__ wa, const float* __restrict__ ba,
    const float* __restrict__ wb, const float* __restrict__ bb,
    const float* __restrict__ wo,
    float* __restrict__ outs, float* __restrict__ alph)
{
  // ---- LDS: ~41 KB (two independent tile pipelines) ----
  __shared__ __attribute__((aligned(16))) _Float16 c0[TPB][2][SPB*LDK0];  // [tile][parity]
  __shared__ __attribute__((aligned(16))) _Float16 cP[TPB][SPB*LDK];
  __shared__ __attribute__((aligned(16))) _Float16 cQ[TPB][SPB*LDK];
  __shared__ __attribute__((aligned(16))) _Float16 cG[TPB][SPB*LDK];
  __shared__ __attribute__((aligned(16))) float nrm[TPB][2][SPB];

  const int tid = threadIdx.x;
  const int wv = tid >> 6;       // wave 0..15
  const int tl = wv >> 3;        // tile 0/1
  const int role = wv & 7;       // role 0..7 within tile (same as R7 wave id)
  const int ln = tid & 63;
  const int mn = ln & 15;
  const int qd = ln >> 4;
  const int q8 = qd * 8;
  const int n  = role * 16 + mn; // col for WIDTH=128 layers (role owns 16 cols)
  const int sgbase = (int)blockIdx.x * (SPB*TPB) + tl * SPB;

  float tmp[8];

  // ---------------- one-time weight fragments (registers, per wave) ----------------
  v8h B0[3][2];
  #pragma unroll
  for (int kf = 0; kf < 3; kf++)
    #pragma unroll
    for (int br = 0; br < 2; br++){
      const float* W = br ? w20 : w10;
      #pragma unroll
      for (int j = 0; j < 8; j++){
        int k = kf*32 + q8 + j;
        int r = (k < 6) ? k : ((k >= 8 && k < 72) ? (k - 2) : -1);
        tmp[j] = (r >= 0) ? W[r*WIDTH + n] : 0.0f;
      }
      make_frag1(tmp, B0[kf][br]);
    }

  v8h B1[4][2], B2[4][2];
  #pragma unroll
  for (int kf = 0; kf < 4; kf++)
    #pragma unroll
    for (int br = 0; br < 2; br++){
      const float* W = br ? w21 : w11;
      #pragma unroll
      for (int j = 0; j < 8; j++)
        tmp[j] = W[(kf*32 + q8 + j)*WIDTH + n];
      make_frag1(tmp, B1[kf][br]);
      const float* V = br ? w22 : w12;
      #pragma unroll
      for (int j = 0; j < 8; j++)
        tmp[j] = V[(kf*32 + q8 + j)*WIDTH + n];
      make_frag1(tmp, B2[kf][br]);
    }

  // D-phase: role (role&3) owns units u..u+15; wa hi+lo (alpha path), wb single (beta)
  const int u = (role & 3) * 16 + mn;
  v8h Bah[4], Bal[4], Bbh[4];
  #pragma unroll
  for (int kf = 0; kf < 4; kf++){
    #pragma unroll
    for (int j = 0; j < 8; j++)
      tmp[j] = wa[(kf*32 + q8 + j)*UNITS + u];
    make_frag2(tmp, Bah[kf], Bal[kf]);
    #pragma unroll
    for (int j = 0; j < 8; j++)
      tmp[j] = wb[(kf*32 + q8 + j)*UNITS + u];
    make_frag1(tmp, Bbh[kf]);
  }
  const float bsa = ba[u];
  const float bsb = bb[u];

  // wout (K=64 over h, N=6 padded to 16): single fp16 (used by role 7)
  v8h Woh0, Woh1;
  #pragma unroll
  for (int j = 0; j < 8; j++)
    tmp[j] = (mn < DOUT) ? wo[(q8 + j)*DOUT + mn] : 0.0f;
  make_frag1(tmp, Woh0);
  #pragma unroll
  for (int j = 0; j < 8; j++)
    tmp[j] = (mn < DOUT) ? wo[(32 + q8 + j)*DOUT + mn] : 0.0f;
  make_frag1(tmp, Woh1);

  const float bs0a = b10[n], bs0b = b20[n];
  const float bs1a = b11[n], bs1b = b21[n];
  const float bs2a = b12[n], bs2b = b22[n];

  // hoisted global-store bases
  float* alp  = alph + ((size_t)(sgbase + qd*4) * TB) * UNITS + u;   // roles 0-3
  float* outp = outs + ((size_t)(sgbase + qd*4) * TB) * DOUT + mn;   // role 7

  // per-tile LDS views
  _Float16* cPt = cP[tl];
  _Float16* cQt = cQ[tl];
  _Float16* cGt = cG[tl];

  // ---------------- init ----------------
  for (int i = tid; i < TPB*2*SPB*LDK0; i += 1024) ((_Float16*)c0)[i] = (_Float16)0.0f;
  __syncthreads();

  // h persistent in registers of roles 0-3 (C-layout: col=unit=u, row=sample=qd*4+r)
  float hreg[4];
  if (role < 4){
    #pragma unroll
    for (int r = 0; r < 4; r++){
      int s = qd*4 + r;
      float v = initF[(size_t)(sgbase + s)*(2 + UNITS) + 2 + u];
      hreg[r] = v;
      c0[tl][0][s*LDK0 + 8 + u] = (_Float16)v;
    }
  }
  float xv0=0, xv1=0, xv2=0, xv3=0, xv4=0, xv5=0;
  if (role == 4 && ln < 16){
    const float* xp = x + (size_t)(sgbase + ln)*TB*D_IN;
    float a0=xp[0], a1=xp[1], a2=xp[2], a3=xp[3], a4=xp[4], a5=xp[5];
    float nv = sqrtf(a0*a0 + a1*a1 + a2*a2 + a3*a3 + a4*a4 + a5*a5);
    nrm[tl][0][ln] = nv;
    float inv = 1.0f / (nv + EPSF);
    c0[tl][0][ln*LDK0 + 0] = (_Float16)(a0*inv);
    c0[tl][0][ln*LDK0 + 1] = (_Float16)(a1*inv);
    c0[tl][0][ln*LDK0 + 2] = (_Float16)(a2*inv);
    c0[tl][0][ln*LDK0 + 3] = (_Float16)(a3*inv);
    c0[tl][0][ln*LDK0 + 4] = (_Float16)(a4*inv);
    c0[tl][0][ln*LDK0 + 5] = (_Float16)(a5*inv);
    xv0 = xp[6]; xv1 = xp[7]; xv2 = xp[8]; xv3 = xp[9]; xv4 = xp[10]; xv5 = xp[11];  // x(t=1)
  }
  __syncthreads();

  auto wout_phase = [&](const _Float16* cb, int tt){
    v8h ah0 = *(const v8h*)(cb + mn*LDK0 + 8 + q8);
    v8h ah1 = *(const v8h*)(cb + mn*LDK0 + 40 + q8);
    v4f acc = {0.f, 0.f, 0.f, 0.f};
    acc = MFMAH(ah0, Woh0, acc);
    acc = MFMAH(ah1, Woh1, acc);
    if (mn < DOUT){
      #pragma unroll
      for (int r = 0; r < 4; r++)
        outp[(size_t)r*TB*DOUT + (size_t)tt*DOUT] = acc[r];
    }
  };

  // ================= time loop (4 LDS-only barriers/step, 2 tiles in flight) =================
  for (int t = 0; t < TB; t++){
    const int p = t & 1;
    const _Float16* c0r = c0[tl][p];
    _Float16* c0w = c0[tl][p ^ 1];

    // ---- Phase A: L0 (c0[p] -> cP) ----
    {
      v8h ah[3];
      #pragma unroll
      for (int kf = 0; kf < 3; kf++)
        ah[kf] = *(const v8h*)(c0r + mn*LDK0 + kf*32 + q8);
      v4f acc0 = {bs0a, bs0a, bs0a, bs0a};
      v4f acc1 = {bs0b, bs0b, bs0b, bs0b};
      #pragma unroll
      for (int kf = 0; kf < 3; kf++){
        acc0 = MFMAH(ah[kf], B0[kf][0], acc0);
        acc1 = MFMAH(ah[kf], B0[kf][1], acc1);
      }
      #pragma unroll
      for (int r = 0; r < 4; r++)
        cPt[(qd*4 + r)*LDK + n] = (_Float16)(tanh_r(acc0[r]) * tanh_r(acc1[r]));
    }
    BARRIER_LDS();  // b1

    // ---- Phase B: L1 (cP -> cQ) ----
    {
      v8h ah[4];
      #pragma unroll
      for (int kf = 0; kf < 4; kf++)
        ah[kf] = *(const v8h*)(cPt + mn*LDK + kf*32 + q8);
      v4f acc0 = {bs1a, bs1a, bs1a, bs1a};
      v4f acc1 = {bs1b, bs1b, bs1b, bs1b};
      #pragma unroll
      for (int kf = 0; kf < 4; kf++){
        acc0 = MFMAH(ah[kf], B1[kf][0], acc0);
        acc1 = MFMAH(ah[kf], B1[kf][1], acc1);
      }
      #pragma unroll
      for (int r = 0; r < 4; r++)
        cQt[(qd*4 + r)*LDK + n] = (_Float16)(tanh_r(acc0[r]) * tanh_r(acc1[r]));
    }
    BARRIER_LDS();  // b2

    // ---- Phase C: L2 (cQ -> g), g = tanh(x1*x2) ----
    {
      v8h ah[4];
      #pragma unroll
      for (int kf = 0; kf < 4; kf++)
        ah[kf] = *(const v8h*)(cQt + mn*LDK + kf*32 + q8);
      v4f acc0 = {bs2a, bs2a, bs2a, bs2a};
      v4f acc1 = {bs2b, bs2b, bs2b, bs2b};
      #pragma unroll
      for (int kf = 0; kf < 4; kf++){
        acc0 = MFMAH(ah[kf], B2[kf][0], acc0);
        acc1 = MFMAH(ah[kf], B2[kf][1], acc1);
      }
      #pragma unroll
      for (int r = 0; r < 4; r++)
        cGt[(qd*4 + r)*LDK + n] = (_Float16)tanh_r(acc0[r] * acc1[r]);
    }
    BARRIER_LDS();  // b3

    // ---- Phase D ----
    if (role < 4){
      v8h gh[4];
      #pragma unroll
      for (int kf = 0; kf < 4; kf++)
        gh[kf] = *(const v8h*)(cGt + mn*LDK + kf*32 + q8);
      v4f pA0 = {bsa, bsa, bsa, bsa};
      v4f pA1 = {0.f, 0.f, 0.f, 0.f};
      v4f pB  = {bsb, bsb, bsb, bsb};
      #pragma unroll
      for (int kf = 0; kf < 2; kf++){
        pA0 = MFMAH(gh[kf], Bah[kf], pA0);
        pA0 = MFMAH(gh[kf], Bal[kf], pA0);
        pA1 = MFMAH(gh[kf+2], Bah[kf+2], pA1);
        pA1 = MFMAH(gh[kf+2], Bal[kf+2], pA1);
        pB  = MFMAH(gh[2*kf],   Bbh[2*kf],   pB);
        pB  = MFMAH(gh[2*kf+1], Bbh[2*kf+1], pB);
      }
      #pragma unroll
      for (int r = 0; r < 4; r++){
        int s = qd*4 + r;
        float nv = nrm[tl][p][s];
        float alpha = __expf(pA0[r] + pA1[r]);
        float beta  = tanh_r(pB[r]);
        float dec   = __expf(-alpha * nv);
        float h = dec * (hreg[r] - beta) + beta;
        hreg[r] = h;
        c0w[s*LDK0 + 8 + u] = (_Float16)h;
        alp[(size_t)r*TB*UNITS + ((size_t)t << 6)] = alpha;
      }
    } else if (role == 7){
      if (t > 0) wout_phase(c0r, t - 1);
    } else if (role == 4 && ln < 16){
      float nv2 = sqrtf(xv0*xv0 + xv1*xv1 + xv2*xv2 + xv3*xv3 + xv4*xv4 + xv5*xv5);
      nrm[tl][p ^ 1][ln] = nv2;
      float inv = 1.0f / (nv2 + EPSF);
      c0w[ln*LDK0 + 0] = (_Float16)(xv0*inv);
      c0w[ln*LDK0 + 1] = (_Float16)(xv1*inv);
      c0w[ln*LDK0 + 2] = (_Float16)(xv2*inv);
      c0w[ln*LDK0 + 3] = (_Float16)(xv3*inv);
      c0w[ln*LDK0 + 4] = (_Float16)(xv4*inv);
      c0w[ln*LDK0 + 5] = (_Float16)(xv5*inv);
      int tn = t + 2; if (tn > TB - 1) tn = TB - 1;
      const float* xp = x + ((size_t)(sgbase + ln)*TB + (size_t)tn)*D_IN;
      xv0 = xp[0]; xv1 = xp[1]; xv2 = xp[2]; xv3 = xp[3]; xv4 = xp[4]; xv5 = xp[5];
    }
    BARRIER_LDS();  // b4
  }

  // final wout(TB-1): h(TB-1) sits in c0[tl][0]
  if (role == 7) wout_phase(c0[tl][TB & 1], TB - 1);
}

extern "C" void kernel_launch(void* const* d_in, const int* in_sizes, int n_in,
                              void* d_out, int out_size, void* d_ws, size_t ws_size,
                              hipStream_t stream) {
  const float* x    = (const float*)d_in[0];
  const float* iF   = (const float*)d_in[1];
  const float* w10  = (const float*)d_in[2];
  const float* b10  = (const float*)d_in[3];
  const float* w20  = (const float*)d_in[4];
  const float* b20  = (const float*)d_in[5];
  const float* w11  = (const float*)d_in[6];
  const float* b11  = (const float*)d_in[7];
  const float* w21  = (const float*)d_in[8];
  const float* b21  = (const float*)d_in[9];
  const float* w12  = (const float*)d_in[10];
  const float* b12  = (const float*)d_in[11];
  const float* w22  = (const float*)d_in[12];
  const float* b22  = (const float*)d_in[13];
  const float* wa   = (const float*)d_in[14];
  const float* ba   = (const float*)d_in[15];
  const float* wb   = (const float*)d_in[16];
  const float* bb   = (const float*)d_in[17];
  const float* wo   = (const float*)d_in[18];

  float* outs = (float*)d_out;
  float* alph = outs + (size_t)NB*TB*DOUT;

  lmsc_kernel<<<NB/(SPB*TPB), 1024, 0, stream>>>(x, iF,
      w10, b10, w20, b20, w11, b11, w21, b21, w12, b12, w22, b22,
      wa, ba, wb, bb, wo, outs, alph);
}

// Round 9
// 12640.069 us; speedup vs baseline: 1.0018x; 1.0018x over previous
//
#include <hip/hip_runtime.h>
#include <stdint.h>
#include <stddef.h>

#define NB 1024
#define TB 1024
#define D_IN 6
#define UNITS 64
#define WIDTH 128
#define DOUT 6
#define EPSF 1e-8f
#define SPB 16          // samples per tile (one 16-row MFMA tile)
#define TPB 2           // tiles per block
#define LDK0 108        // c0 row stride (halfs): conflict-free (54 dw == 22 mod 32)
#define LDK 140         // cP/cQ/cG row stride (halfs): conflict-free (70 dw == 6 mod 32)

typedef _Float16 v8h __attribute__((ext_vector_type(8)));
typedef float v4f __attribute__((ext_vector_type(4)));

#define MFMAH(A,Bf,C) __builtin_amdgcn_mfma_f32_16x16x32_f16((A),(Bf),(C),0,0,0)

// LDS-only barrier: orders LDS across the block, does NOT drain vmcnt.
#define BARRIER_LDS() asm volatile("s_waitcnt lgkmcnt(0)\n\ts_barrier" ::: "memory")

__device__ __forceinline__ float rcp_fast(float x){ return __builtin_amdgcn_rcpf(x); }

// Pade(7,6) tanh on VALU pipe (1 fast-rcp, no exp). Clamp +-5.
__device__ __forceinline__ float tanh_r(float x){
  float t = fminf(fmaxf(x, -5.0f), 5.0f);
  float s = t * t;
  float num = t * fmaf(s, fmaf(s, (s + 378.0f), 17325.0f), 135135.0f);
  float den = fmaf(s, fmaf(s, fmaf(s, 28.0f, 3150.0f), 62370.0f), 135135.0f);
  return num * rcp_fast(den);
}

__device__ __forceinline__ void make_frag1(const float* vals, v8h& hv){
  #pragma unroll
  for (int j = 0; j < 8; j++) hv[j] = (_Float16)vals[j];
}
__device__ __forceinline__ void make_frag2(const float* vals, v8h& hv, v8h& lv){
  #pragma unroll
  for (int j = 0; j < 8; j++){
    _Float16 h = (_Float16)vals[j];
    hv[j] = h;
    lv[j] = (_Float16)(vals[j] - (float)h);
  }
}

// __launch_bounds__ 2nd arg is CUDA-style min-BLOCKS-per-CU on this toolchain
// (empirical: (512,2)->128 VGPR cap, (1024,4)->64 VGPR cap/spill disaster).
// (1024,1): 1 block x 16 waves = 4 waves/EU -> 128 VGPR cap. Exactly what we need.
__global__ __launch_bounds__(1024, 1) void lmsc_kernel(
    const float* __restrict__ x, const float* __restrict__ initF,
    const float* __restrict__ w10, const float* __restrict__ b10,
    const float* __restrict__ w20, const float* __restrict__ b20,
    const float* __restrict__ w11, const float* __restrict__ b11,
    const float* __restrict__ w21, const float* __restrict__ b21,
    const float* __restrict__ w12, const float* __restrict__ b12,
    const float* __restrict__ w22, const float* __restrict__ b22,
    const float* __restrict__ wa, const float* __restrict__ ba,
    const float* __restrict__ wb, const float* __restrict__ bb,
    const float* __restrict__ wo,
    float* __restrict__ outs, float* __restrict__ alph)
{
  // ---- LDS: ~41 KB (two independent tile pipelines) ----
  __shared__ __attribute__((aligned(16))) _Float16 c0[TPB][2][SPB*LDK0];  // [tile][parity]
  __shared__ __attribute__((aligned(16))) _Float16 cP[TPB][SPB*LDK];
  __shared__ __attribute__((aligned(16))) _Float16 cQ[TPB][SPB*LDK];
  __shared__ __attribute__((aligned(16))) _Float16 cG[TPB][SPB*LDK];
  __shared__ __attribute__((aligned(16))) float nrm[TPB][2][SPB];

  const int tid = threadIdx.x;
  const int wv = tid >> 6;       // wave 0..15
  const int tl = wv >> 3;        // tile 0/1
  const int role = wv & 7;       // role 0..7 within tile (same as R7 wave id)
  const int ln = tid & 63;
  const int mn = ln & 15;
  const int qd = ln >> 4;
  const int q8 = qd * 8;
  const int n  = role * 16 + mn; // col for WIDTH=128 layers (role owns 16 cols)
  const int sgbase = (int)blockIdx.x * (SPB*TPB) + tl * SPB;

  float tmp[8];

  // ---------------- one-time weight fragments (registers, per wave) ----------------
  v8h B0[3][2];
  #pragma unroll
  for (int kf = 0; kf < 3; kf++)
    #pragma unroll
    for (int br = 0; br < 2; br++){
      const float* W = br ? w20 : w10;
      #pragma unroll
      for (int j = 0; j < 8; j++){
        int k = kf*32 + q8 + j;
        int r = (k < 6) ? k : ((k >= 8 && k < 72) ? (k - 2) : -1);
        tmp[j] = (r >= 0) ? W[r*WIDTH + n] : 0.0f;
      }
      make_frag1(tmp, B0[kf][br]);
    }

  v8h B1[4][2], B2[4][2];
  #pragma unroll
  for (int kf = 0; kf < 4; kf++)
    #pragma unroll
    for (int br = 0; br < 2; br++){
      const float* W = br ? w21 : w11;
      #pragma unroll
      for (int j = 0; j < 8; j++)
        tmp[j] = W[(kf*32 + q8 + j)*WIDTH + n];
      make_frag1(tmp, B1[kf][br]);
      const float* V = br ? w22 : w12;
      #pragma unroll
      for (int j = 0; j < 8; j++)
        tmp[j] = V[(kf*32 + q8 + j)*WIDTH + n];
      make_frag1(tmp, B2[kf][br]);
    }

  // D-phase: role (role&3) owns units u..u+15; wa hi+lo (alpha path), wb single (beta)
  const int u = (role & 3) * 16 + mn;
  v8h Bah[4], Bal[4], Bbh[4];
  #pragma unroll
  for (int kf = 0; kf < 4; kf++){
    #pragma unroll
    for (int j = 0; j < 8; j++)
      tmp[j] = wa[(kf*32 + q8 + j)*UNITS + u];
    make_frag2(tmp, Bah[kf], Bal[kf]);
    #pragma unroll
    for (int j = 0; j < 8; j++)
      tmp[j] = wb[(kf*32 + q8 + j)*UNITS + u];
    make_frag1(tmp, Bbh[kf]);
  }
  const float bsa = ba[u];
  const float bsb = bb[u];

  // wout (K=64 over h, N=6 padded to 16): single fp16 (used by role 7)
  v8h Woh0, Woh1;
  #pragma unroll
  for (int j = 0; j < 8; j++)
    tmp[j] = (mn < DOUT) ? wo[(q8 + j)*DOUT + mn] : 0.0f;
  make_frag1(tmp, Woh0);
  #pragma unroll
  for (int j = 0; j < 8; j++)
    tmp[j] = (mn < DOUT) ? wo[(32 + q8 + j)*DOUT + mn] : 0.0f;
  make_frag1(tmp, Woh1);

  const float bs0a = b10[n], bs0b = b20[n];
  const float bs1a = b11[n], bs1b = b21[n];
  const float bs2a = b12[n], bs2b = b22[n];

  // hoisted global-store bases
  float* alp  = alph + ((size_t)(sgbase + qd*4) * TB) * UNITS + u;   // roles 0-3
  float* outp = outs + ((size_t)(sgbase + qd*4) * TB) * DOUT + mn;   // role 7

  // per-tile LDS views
  _Float16* cPt = cP[tl];
  _Float16* cQt = cQ[tl];
  _Float16* cGt = cG[tl];

  // ---------------- init ----------------
  for (int i = tid; i < TPB*2*SPB*LDK0; i += 1024) ((_Float16*)c0)[i] = (_Float16)0.0f;
  __syncthreads();

  // h persistent in registers of roles 0-3 (C-layout: col=unit=u, row=sample=qd*4+r)
  float hreg[4];
  if (role < 4){
    #pragma unroll
    for (int r = 0; r < 4; r++){
      int s = qd*4 + r;
      float v = initF[(size_t)(sgbase + s)*(2 + UNITS) + 2 + u];
      hreg[r] = v;
      c0[tl][0][s*LDK0 + 8 + u] = (_Float16)v;
    }
  }
  float xv0=0, xv1=0, xv2=0, xv3=0, xv4=0, xv5=0;
  if (role == 4 && ln < 16){
    const float* xp = x + (size_t)(sgbase + ln)*TB*D_IN;
    float a0=xp[0], a1=xp[1], a2=xp[2], a3=xp[3], a4=xp[4], a5=xp[5];
    float nv = sqrtf(a0*a0 + a1*a1 + a2*a2 + a3*a3 + a4*a4 + a5*a5);
    nrm[tl][0][ln] = nv;
    float inv = 1.0f / (nv + EPSF);
    c0[tl][0][ln*LDK0 + 0] = (_Float16)(a0*inv);
    c0[tl][0][ln*LDK0 + 1] = (_Float16)(a1*inv);
    c0[tl][0][ln*LDK0 + 2] = (_Float16)(a2*inv);
    c0[tl][0][ln*LDK0 + 3] = (_Float16)(a3*inv);
    c0[tl][0][ln*LDK0 + 4] = (_Float16)(a4*inv);
    c0[tl][0][ln*LDK0 + 5] = (_Float16)(a5*inv);
    xv0 = xp[6]; xv1 = xp[7]; xv2 = xp[8]; xv3 = xp[9]; xv4 = xp[10]; xv5 = xp[11];  // x(t=1)
  }
  __syncthreads();

  auto wout_phase = [&](const _Float16* cb, int tt){
    v8h ah0 = *(const v8h*)(cb + mn*LDK0 + 8 + q8);
    v8h ah1 = *(const v8h*)(cb + mn*LDK0 + 40 + q8);
    v4f acc = {0.f, 0.f, 0.f, 0.f};
    acc = MFMAH(ah0, Woh0, acc);
    acc = MFMAH(ah1, Woh1, acc);
    if (mn < DOUT){
      #pragma unroll
      for (int r = 0; r < 4; r++)
        outp[(size_t)r*TB*DOUT + (size_t)tt*DOUT] = acc[r];
    }
  };

  // ================= time loop (4 LDS-only barriers/step, 2 tiles in flight) =================
  for (int t = 0; t < TB; t++){
    const int p = t & 1;
    const _Float16* c0r = c0[tl][p];
    _Float16* c0w = c0[tl][p ^ 1];

    // ---- Phase A: L0 (c0[p] -> cP) ----
    {
      v8h ah[3];
      #pragma unroll
      for (int kf = 0; kf < 3; kf++)
        ah[kf] = *(const v8h*)(c0r + mn*LDK0 + kf*32 + q8);
      v4f acc0 = {bs0a, bs0a, bs0a, bs0a};
      v4f acc1 = {bs0b, bs0b, bs0b, bs0b};
      #pragma unroll
      for (int kf = 0; kf < 3; kf++){
        acc0 = MFMAH(ah[kf], B0[kf][0], acc0);
        acc1 = MFMAH(ah[kf], B0[kf][1], acc1);
      }
      #pragma unroll
      for (int r = 0; r < 4; r++)
        cPt[(qd*4 + r)*LDK + n] = (_Float16)(tanh_r(acc0[r]) * tanh_r(acc1[r]));
    }
    BARRIER_LDS();  // b1

    // ---- Phase B: L1 (cP -> cQ) ----
    {
      v8h ah[4];
      #pragma unroll
      for (int kf = 0; kf < 4; kf++)
        ah[kf] = *(const v8h*)(cPt + mn*LDK + kf*32 + q8);
      v4f acc0 = {bs1a, bs1a, bs1a, bs1a};
      v4f acc1 = {bs1b, bs1b, bs1b, bs1b};
      #pragma unroll
      for (int kf = 0; kf < 4; kf++){
        acc0 = MFMAH(ah[kf], B1[kf][0], acc0);
        acc1 = MFMAH(ah[kf], B1[kf][1], acc1);
      }
      #pragma unroll
      for (int r = 0; r < 4; r++)
        cQt[(qd*4 + r)*LDK + n] = (_Float16)(tanh_r(acc0[r]) * tanh_r(acc1[r]));
    }
    BARRIER_LDS();  // b2

    // ---- Phase C: L2 (cQ -> g), g = tanh(x1*x2) ----
    {
      v8h ah[4];
      #pragma unroll
      for (int kf = 0; kf < 4; kf++)
        ah[kf] = *(const v8h*)(cQt + mn*LDK + kf*32 + q8);
      v4f acc0 = {bs2a, bs2a, bs2a, bs2a};
      v4f acc1 = {bs2b, bs2b, bs2b, bs2b};
      #pragma unroll
      for (int kf = 0; kf < 4; kf++){
        acc0 = MFMAH(ah[kf], B2[kf][0], acc0);
        acc1 = MFMAH(ah[kf], B2[kf][1], acc1);
      }
      #pragma unroll
      for (int r = 0; r < 4; r++)
        cGt[(qd*4 + r)*LDK + n] = (_Float16)tanh_r(acc0[r] * acc1[r]);
    }
    BARRIER_LDS();  // b3

    // ---- Phase D ----
    if (role < 4){
      v8h gh[4];
      #pragma unroll
      for (int kf = 0; kf < 4; kf++)
        gh[kf] = *(const v8h*)(cGt + mn*LDK + kf*32 + q8);
      v4f pA0 = {bsa, bsa, bsa, bsa};
      v4f pA1 = {0.f, 0.f, 0.f, 0.f};
      v4f pB  = {bsb, bsb, bsb, bsb};
      #pragma unroll
      for (int kf = 0; kf < 2; kf++){
        pA0 = MFMAH(gh[kf], Bah[kf], pA0);
        pA0 = MFMAH(gh[kf], Bal[kf], pA0);
        pA1 = MFMAH(gh[kf+2], Bah[kf+2], pA1);
        pA1 = MFMAH(gh[kf+2], Bal[kf+2], pA1);
        pB  = MFMAH(gh[2*kf],   Bbh[2*kf],   pB);
        pB  = MFMAH(gh[2*kf+1], Bbh[2*kf+1], pB);
      }
      #pragma unroll
      for (int r = 0; r < 4; r++){
        int s = qd*4 + r;
        float nv = nrm[tl][p][s];
        float alpha = __expf(pA0[r] + pA1[r]);
        float beta  = tanh_r(pB[r]);
        float dec   = __expf(-alpha * nv);
        float h = dec * (hreg[r] - beta) + beta;
        hreg[r] = h;
        c0w[s*LDK0 + 8 + u] = (_Float16)h;
        alp[(size_t)r*TB*UNITS + ((size_t)t << 6)] = alpha;
      }
    } else if (role == 7){
      if (t > 0) wout_phase(c0r, t - 1);
    } else if (role == 4 && ln < 16){
      float nv2 = sqrtf(xv0*xv0 + xv1*xv1 + xv2*xv2 + xv3*xv3 + xv4*xv4 + xv5*xv5);
      nrm[tl][p ^ 1][ln] = nv2;
      float inv = 1.0f / (nv2 + EPSF);
      c0w[ln*LDK0 + 0] = (_Float16)(xv0*inv);
      c0w[ln*LDK0 + 1] = (_Float16)(xv1*inv);
      c0w[ln*LDK0 + 2] = (_Float16)(xv2*inv);
      c0w[ln*LDK0 + 3] = (_Float16)(xv3*inv);
      c0w[ln*LDK0 + 4] = (_Float16)(xv4*inv);
      c0w[ln*LDK0 + 5] = (_Float16)(xv5*inv);
      int tn = t + 2; if (tn > TB - 1) tn = TB - 1;
      const float* xp = x + ((size_t)(sgbase + ln)*TB + (size_t)tn)*D_IN;
      xv0 = xp[0]; xv1 = xp[1]; xv2 = xp[2]; xv3 = xp[3]; xv4 = xp[4]; xv5 = xp[5];
    }
    BARRIER_LDS();  // b4
  }

  // final wout(TB-1): h(TB-1) sits in c0[tl][0]
  if (role == 7) wout_phase(c0[tl][TB & 1], TB - 1);
}

extern "C" void kernel_launch(void* const* d_in, const int* in_sizes, int n_in,
                              void* d_out, int out_size, void* d_ws, size_t ws_size,
                              hipStream_t stream) {
  const float* x    = (const float*)d_in[0];
  const float* iF   = (const float*)d_in[1];
  const float* w10  = (const float*)d_in[2];
  const float* b10  = (const float*)d_in[3];
  const float* w20  = (const float*)d_in[4];
  const float* b20  = (const float*)d_in[5];
  const float* w11  = (const float*)d_in[6];
  const float* b11  = (const float*)d_in[7];
  const float* w21  = (const float*)d_in[8];
  const float* b21  = (const float*)d_in[9];
  const float* w12  = (const float*)d_in[10];
  const float* b12  = (const float*)d_in[11];
  const float* w22  = (const float*)d_in[12];
  const float* b22  = (const float*)d_in[13];
  const float* wa   = (const float*)d_in[14];
  const float* ba   = (const float*)d_in[15];
  const float* wb   = (const float*)d_in[16];
  const float* bb   = (const float*)d_in[17];
  const float* wo   = (const float*)d_in[18];

  float* outs = (float*)d_out;
  float* alph = outs + (size_t)NB*TB*DOUT;

  lmsc_kernel<<<NB/(SPB*TPB), 1024, 0, stream>>>(x, iF,
      w10, b10, w20, b20, w11, b11, w21, b21, w12, b12, w22, b22,
      wa, ba, wb, bb, wo, outs, alph);
}